// Round 3
// baseline (10392.538 us; speedup 1.0000x reference)
//
#include <hip/hip_runtime.h>

// ScaleNet gated residual block, MI355X (fp32 I/O and math — reference is jnp.float32).
// K1: both mask convs (f64 accum, shared x reads, LDS weights)
// K2: conv1 + BN1 + ReLU + *m1 -> tmp (fp32, in d_ws)
// K3: conv2 + BN2 + *m2 + residual + ReLU -> d_out (fp32)
// Workspace-adaptive: full-batch tmp if ws_size allows, else per-image loop.

#define NB 32
#define C  256
#define H  56
#define W  56
#define HW (H*W)      // 3136
#define EPSV 1e-5f

// ---------------- K1: masks -------------------------------------------------
// 1 thread per pixel, computes both mask convs sharing x reads.
// grid = N*HW/256 = 392 blocks exactly.
__global__ __launch_bounds__(256) void mask_kernel(
    const float* __restrict__ x,
    const float* __restrict__ wm1, const float* __restrict__ bm1,
    const float* __restrict__ wm2, const float* __restrict__ bm2,
    float* __restrict__ m1, float* __restrict__ m2)
{
    __shared__ float ws1[C*9], ws2[C*9];
    for (int i = threadIdx.x; i < C*9; i += 256) {
        ws1[i] = wm1[i];
        ws2[i] = wm2[i];
    }
    __syncthreads();

    int idx = blockIdx.x * 256 + threadIdx.x;   // 0 .. N*HW-1 (exact)
    int w_ = idx % W;
    int t  = idx / W;
    int h  = t % H;
    int n  = t / H;

    double a1 = (double)bm1[0];
    double a2 = (double)bm2[0];
    const float* xp = x + (size_t)n * C * HW;
    for (int ci = 0; ci < C; ++ci) {
        const float* bp = xp + (size_t)ci * HW;
        #pragma unroll
        for (int ky = 0; ky < 3; ++ky) {
            int y = h + ky - 1;
            if ((unsigned)y >= (unsigned)H) continue;
            #pragma unroll
            for (int kx = 0; kx < 3; ++kx) {
                int xx = w_ + kx - 1;
                if ((unsigned)xx >= (unsigned)W) continue;
                double xv = (double)bp[y*W + xx];
                a1 += xv * (double)ws1[ci*9 + ky*3 + kx];
                a2 += xv * (double)ws2[ci*9 + ky*3 + kx];
            }
        }
    }
    // sigmoid(z) > 0.5  <=>  z > 0
    m1[idx] = (a1 > 0.0) ? 1.0f : 0.0f;
    m2[idx] = (a2 > 0.0) ? 1.0f : 0.0f;
}

// ---------------- K2/K3: main convs ----------------------------------------
// 1 thread computes 4 vertically-adjacent outputs (shares input rows).
// Pointers are pre-offset per image in the fallback path (n==0 there).
template<bool SECOND>
__global__ __launch_bounds__(256) void conv_kernel(
    const float* __restrict__ in,     // x (first) or tmp (second)
    const float* __restrict__ wt,     // [C][C][3][3]
    const float* __restrict__ g,  const float* __restrict__ b,
    const float* __restrict__ mu, const float* __restrict__ vv,
    const float* __restrict__ mask,   // [nimg][HW], 0/1
    const float* __restrict__ xres,   // SECOND: residual input
    float* __restrict__ out)          // tmp (first) or final out (second)
{
    int idx = blockIdx.x * 256 + threadIdx.x;
    int w_ = idx % W;
    int t  = idx / W;
    int hg = t % (H/4);
    t /= (H/4);
    int co = t % C;
    int n  = t / C;
    int h0 = hg * 4;

    // per-row masks
    float mv[4];
    #pragma unroll
    for (int r = 0; r < 4; ++r)
        mv[r] = mask[(size_t)n*HW + (h0 + r)*W + w_];
    bool any = (mv[0] + mv[1] + mv[2] + mv[3]) > 0.0f;

    float acc0 = 0.f, acc1 = 0.f, acc2 = 0.f, acc3 = 0.f;

    if (any) {
        const long in_base = (long)n * C * HW;
        const float* wp0 = wt + (size_t)co * C * 9;
        for (int ci = 0; ci < C; ++ci) {
            float xr[6][3];
            #pragma unroll
            for (int r = 0; r < 6; ++r) {
                int y = h0 + r - 1;
                bool yin = (unsigned)y < (unsigned)H;
                long rowoff = in_base + (long)ci*HW + (long)y*W + w_;
                float v0 = 0.f, v1 = 0.f, v2 = 0.f;
                if (yin) {
                    v1 = in[rowoff];
                    if (w_ > 0)     v0 = in[rowoff - 1];
                    if (w_ < W - 1) v2 = in[rowoff + 1];
                }
                xr[r][0] = v0; xr[r][1] = v1; xr[r][2] = v2;
            }
            const float* wp = wp0 + ci * 9;
            float wv[9];
            #pragma unroll
            for (int k = 0; k < 9; ++k) wv[k] = wp[k];
            #pragma unroll
            for (int ky = 0; ky < 3; ++ky) {
                #pragma unroll
                for (int kx = 0; kx < 3; ++kx) {
                    float wk = wv[ky*3 + kx];
                    acc0 += xr[0 + ky][kx] * wk;
                    acc1 += xr[1 + ky][kx] * wk;
                    acc2 += xr[2 + ky][kx] * wk;
                    acc3 += xr[3 + ky][kx] * wk;
                }
            }
        }
    }

    float s  = g[co] * rsqrtf(vv[co] + EPSV);
    float tt = b[co] - mu[co] * s;
    float accs[4] = {acc0, acc1, acc2, acc3};

    #pragma unroll
    for (int r = 0; r < 4; ++r) {
        size_t oidx = ((size_t)(n*C + co) * H + (h0 + r)) * W + w_;
        if (SECOND) {
            float v = (mv[r] != 0.0f) ? (accs[r]*s + tt) : 0.0f;
            v += xres[oidx];
            out[oidx] = fmaxf(v, 0.0f);
        } else {
            float v = (mv[r] != 0.0f) ? fmaxf(accs[r]*s + tt, 0.0f) : 0.0f;
            out[oidx] = v;
        }
    }
}

extern "C" void kernel_launch(void* const* d_in, const int* in_sizes, int n_in,
                              void* d_out, int out_size, void* d_ws, size_t ws_size,
                              hipStream_t stream) {
    const float* x   = (const float*)d_in[0];
    const float* w1  = (const float*)d_in[1];
    const float* w2  = (const float*)d_in[2];
    const float* g1  = (const float*)d_in[3];
    const float* b1  = (const float*)d_in[4];
    const float* mu1 = (const float*)d_in[5];
    const float* v1  = (const float*)d_in[6];
    const float* g2  = (const float*)d_in[7];
    const float* b2  = (const float*)d_in[8];
    const float* mu2 = (const float*)d_in[9];
    const float* v2  = (const float*)d_in[10];
    const float* wm1 = (const float*)d_in[11];
    const float* bm1 = (const float*)d_in[12];
    const float* wm2 = (const float*)d_in[13];
    const float* bm2 = (const float*)d_in[14];
    float* out = (float*)d_out;

    const size_t maskElems = (size_t)NB * HW;          // 100,352
    float* m1  = (float*)d_ws;                         // [N*HW]
    float* m2  = m1 + maskElems;                       // [N*HW]
    float* tmp = m2 + maskElems;                       // fp32 tmp

    const size_t need_full = (2*maskElems + (size_t)NB*C*HW) * sizeof(float); // ~103.6 MB

    mask_kernel<<<(NB*HW)/256, 256, 0, stream>>>(x, wm1, bm1, wm2, bm2, m1, m2);

    if (ws_size >= need_full) {
        const int total = NB * C * (H/4) * W;          // 6,422,528
        conv_kernel<false><<<total/256, 256, 0, stream>>>(
            x, w1, g1, b1, mu1, v1, m1, nullptr, tmp);
        conv_kernel<true><<<total/256, 256, 0, stream>>>(
            tmp, w2, g2, b2, mu2, v2, m2, x, out);
    } else {
        // Per-image loop: tmp holds one image (C*HW fp32 = 3.2 MB).
        const int per = (C * (H/4) * W) / 256;         // 784 blocks
        for (int nb = 0; nb < NB; ++nb) {
            const float* xn = x + (size_t)nb * C * HW;
            conv_kernel<false><<<per, 256, 0, stream>>>(
                xn, w1, g1, b1, mu1, v1, m1 + (size_t)nb * HW, nullptr, tmp);
            conv_kernel<true><<<per, 256, 0, stream>>>(
                tmp, w2, g2, b2, mu2, v2, m2 + (size_t)nb * HW, xn,
                out + (size_t)nb * C * HW);
        }
    }
}

// Round 5
// 1088.932 us; speedup vs baseline: 9.5438x; 9.5438x over previous
//
#include <hip/hip_runtime.h>
#include <hip/hip_bf16.h>

// ScaleNet gated residual block, MI355X — bf16 MFMA implicit GEMM.
//  K0 mask_kernel : f64-accum mask convs (sign-exact vs np ref)  -> m1, m2
//  K1 transpose   : x NCHW f32 -> xb NHWC bf16 (stored in d_out scratch)
//  K2 pack        : w1,w2 OIHW f32 -> B-frag-ready packed bf16
//  K3 conv_mfma<1>: conv1 + BN1 + ReLU + *m1 -> tmp NHWC bf16 (ws)
//  K4 conv_mfma<0>: conv2 + BN2 + *m2 + residual + ReLU -> d_out NCHW f32

#define NB 32
#define C  256
#define H  56
#define W  56
#define HW (H*W)          // 3136 = 49*64
#define EPSV 1e-5f
#define WELEM (C*C*9)     // 589824 packed elements per conv

typedef __hip_bfloat16 bf16;
typedef __attribute__((ext_vector_type(8))) short  bf16x8;
typedef __attribute__((ext_vector_type(4))) float  floatx4;

// ---------------- K0: masks (unchanged from R3; f64 accumulate) -------------
__global__ __launch_bounds__(256) void mask_kernel(
    const float* __restrict__ x,
    const float* __restrict__ wm1, const float* __restrict__ bm1,
    const float* __restrict__ wm2, const float* __restrict__ bm2,
    float* __restrict__ m1, float* __restrict__ m2)
{
    __shared__ float ws1[C*9], ws2[C*9];
    for (int i = threadIdx.x; i < C*9; i += 256) {
        ws1[i] = wm1[i];
        ws2[i] = wm2[i];
    }
    __syncthreads();

    int idx = blockIdx.x * 256 + threadIdx.x;   // N*HW exact
    int w_ = idx % W;
    int t  = idx / W;
    int h  = t % H;
    int n  = t / H;

    double a1 = (double)bm1[0];
    double a2 = (double)bm2[0];
    const float* xp = x + (size_t)n * C * HW;
    for (int ci = 0; ci < C; ++ci) {
        const float* bp = xp + (size_t)ci * HW;
        #pragma unroll
        for (int ky = 0; ky < 3; ++ky) {
            int y = h + ky - 1;
            if ((unsigned)y >= (unsigned)H) continue;
            #pragma unroll
            for (int kx = 0; kx < 3; ++kx) {
                int xx = w_ + kx - 1;
                if ((unsigned)xx >= (unsigned)W) continue;
                double xv = (double)bp[y*W + xx];
                a1 += xv * (double)ws1[ci*9 + ky*3 + kx];
                a2 += xv * (double)ws2[ci*9 + ky*3 + kx];
            }
        }
    }
    m1[idx] = (a1 > 0.0) ? 1.0f : 0.0f;   // sigmoid(z)>0.5 <=> z>0
    m2[idx] = (a2 > 0.0) ? 1.0f : 0.0f;
}

// ---------------- K1: NCHW f32 -> NHWC bf16 ---------------------------------
__global__ __launch_bounds__(256) void transpose_kernel(
    const float* __restrict__ x, bf16* __restrict__ xb)
{
    __shared__ float tile[64][65];
    int bid = blockIdx.x;             // 32 * 4 * 49
    int pt = bid % 49; bid /= 49;
    int ct = bid % 4;  int n = bid / 4;
    int p0 = pt * 64, c0 = ct * 64;
    int tl = threadIdx.x & 63;
    int tg = threadIdx.x >> 6;        // 0..3
    const float* xp = x + ((size_t)(n*C + c0) * HW) + p0;
    #pragma unroll
    for (int i = 0; i < 16; ++i) {
        int cl = tg*16 + i;
        tile[cl][tl] = xp[(size_t)cl * HW + tl];
    }
    __syncthreads();
    bf16* op = xb + ((size_t)(n*HW + p0) * C) + c0;
    #pragma unroll
    for (int i = 0; i < 16; ++i) {
        int pl = tg*16 + i;
        op[(size_t)pl * C + tl] = __float2bfloat16(tile[tl][pl]);
    }
}

// ---------------- K2: pack weights into B-frag order ------------------------
// layout: [tap(9)][kstep(8)][ntile(16)][lane(64)][8 ci]  (16B per lane)
__global__ __launch_bounds__(256) void pack_kernel(
    const float* __restrict__ w1, const float* __restrict__ w2,
    bf16* __restrict__ w1p, bf16* __restrict__ w2p)
{
    int idx = blockIdx.x * 256 + threadIdx.x;       // 0 .. 2*WELEM-1
    const float* src = (idx < WELEM) ? w1 : w2;
    bf16* dst        = (idx < WELEM) ? w1p : w2p;
    int f = (idx < WELEM) ? idx : idx - WELEM;
    int e  = f & 7;
    int O  = f >> 3;
    int L  = O & 63;
    int j  = (O >> 6) & 15;
    int ks = (O >> 10) & 7;
    int t  = O >> 13;
    int co = j*16 + (L & 15);
    int ci = ks*32 + ((L >> 4) & 3)*8 + e;
    dst[f] = __float2bfloat16(src[((size_t)co*C + ci)*9 + t]);
}

// ---------------- K3/K4: MFMA implicit-GEMM conv ----------------------------
// block: 64 pixels (8x8 tile) x 256 co, 4 waves (64 co each), K chunked 128.
template<bool FIRST>
__global__ __launch_bounds__(256, 2) void conv_mfma(
    const bf16* __restrict__ inb,    // NHWC bf16
    const bf16* __restrict__ wp,     // packed weights
    const float* __restrict__ g,  const float* __restrict__ b,
    const float* __restrict__ mu, const float* __restrict__ vv,
    const float* __restrict__ mask,  // [NB][HW] 0/1
    const float* __restrict__ xres,  // NCHW f32 (SECOND)
    bf16* __restrict__ outb,         // FIRST: tmp NHWC bf16
    float* __restrict__ outf)        // SECOND: NCHW f32
{
    __shared__ uint4 patch4[1700];   // 100 pos * (128 ci + 8 pad) shorts = 27.2 KB
    __shared__ float msk[64];
    short* patch = (short*)patch4;

    int bid  = blockIdx.x;
    int tile = bid % 49;
    int n    = bid / 49;
    int y0 = (tile / 7) * 8;
    int x0 = (tile % 7) * 8;

    int tid = threadIdx.x;
    int L   = tid & 63;
    int wv  = tid >> 6;

    if (tid < 64) {
        int pr = tid >> 3, pc = tid & 7;
        msk[tid] = mask[(size_t)n*HW + (y0+pr)*W + (x0+pc)];
    }

    // per-lane A-fragment base offsets (padded stride 136 shorts/position)
    int m  = L & 15;
    int kb = L >> 4;
    int abase[4];
    #pragma unroll
    for (int mi = 0; mi < 4; ++mi) {
        int p   = mi*16 + m;
        int pos = (p >> 3)*10 + (p & 7);
        abase[mi] = pos*136 + kb*8;
    }

    floatx4 acc[4][4];
    #pragma unroll
    for (int mi = 0; mi < 4; ++mi)
        #pragma unroll
        for (int jj = 0; jj < 4; ++jj)
            acc[mi][jj] = (floatx4){0.f, 0.f, 0.f, 0.f};

    const size_t img_base = (size_t)n * HW * C;

    for (int ck = 0; ck < 2; ++ck) {
        if (ck) __syncthreads();                 // LDS reuse fence
        // ---- stage 10x10 halo patch, 128-ci chunk, into LDS ----
        for (int S = tid; S < 1600; S += 256) {
            int q   = S & 15;
            int pos = S >> 4;
            int r = pos / 10, c = pos - (pos/10)*10;
            int y  = y0 + r - 1;
            int xx = x0 + c - 1;
            uint4 val = make_uint4(0u, 0u, 0u, 0u);
            if ((unsigned)y < (unsigned)H && (unsigned)xx < (unsigned)W)
                val = *(const uint4*)(inb + img_base + (size_t)(y*W + xx)*C + ck*128 + q*8);
            patch4[pos*17 + q] = val;
        }
        __syncthreads();

        // ---- K-loop: 9 taps x 4 ksteps, register-double-buffered B ----
        bf16x8 bcur[4], bnxt[4];
        {
            int ks0 = ck*4;
            #pragma unroll
            for (int jj = 0; jj < 4; ++jj) {
                int jgl = wv*4 + jj;
                bcur[jj] = *(const bf16x8*)(wp + ((size_t)((0*8 + ks0)*16 + jgl)*64 + L)*8);
            }
        }
        for (int gs = 0; gs < 36; ++gs) {
            int t = gs >> 2;
            int s = gs & 3;
            if (gs < 35) {
                int g2 = gs + 1;
                int t2 = g2 >> 2, ks2 = ck*4 + (g2 & 3);
                #pragma unroll
                for (int jj = 0; jj < 4; ++jj) {
                    int jgl = wv*4 + jj;
                    bnxt[jj] = *(const bf16x8*)(wp + ((size_t)((t2*8 + ks2)*16 + jgl)*64 + L)*8);
                }
            }
            int ky = t / 3;
            int dt = ky*10 + (t - ky*3);         // ky*10 + kx
            int aoff = dt*136 + s*32;
            bf16x8 afr[4];
            #pragma unroll
            for (int mi = 0; mi < 4; ++mi)
                afr[mi] = *(const bf16x8*)(patch + abase[mi] + aoff);
            #pragma unroll
            for (int mi = 0; mi < 4; ++mi)
                #pragma unroll
                for (int jj = 0; jj < 4; ++jj)
                    acc[mi][jj] = __builtin_amdgcn_mfma_f32_16x16x32_bf16(
                        afr[mi], bcur[jj], acc[mi][jj], 0, 0, 0);
            #pragma unroll
            for (int jj = 0; jj < 4; ++jj) bcur[jj] = bnxt[jj];
        }
    }

    // ---- epilogue ----
    int quad  = L >> 4;
    int wbase = wv * 64;
    #pragma unroll
    for (int jj = 0; jj < 4; ++jj) {
        int co = wbase + jj*16 + (L & 15);
        float s_ = g[co] * rsqrtf(vv[co] + EPSV);
        float t_ = b[co] - mu[co] * s_;
        #pragma unroll
        for (int mi = 0; mi < 4; ++mi) {
            int pbase = mi*16 + quad*4;
            if (FIRST) {
                #pragma unroll
                for (int r = 0; r < 4; ++r) {
                    int p = pbase + r;
                    float v = acc[mi][jj][r] * s_ + t_;
                    v = fmaxf(v, 0.f) * msk[p];
                    int pg = (y0 + (p >> 3))*W + (x0 + (p & 7));
                    outb[img_base + (size_t)pg*C + co] = __float2bfloat16(v);
                }
            } else {
                int pg = (y0 + (pbase >> 3))*W + (x0 + (pbase & 7));
                size_t oidx = ((size_t)(n*C + co))*HW + pg;
                floatx4 xr = *(const floatx4*)(xres + oidx);
                floatx4 ov;
                #pragma unroll
                for (int r = 0; r < 4; ++r) {
                    float v = acc[mi][jj][r] * s_ + t_;
                    v = v * msk[pbase + r] + xr[r];
                    ov[r] = fmaxf(v, 0.f);
                }
                *(floatx4*)(outf + oidx) = ov;
            }
        }
    }
}

extern "C" void kernel_launch(void* const* d_in, const int* in_sizes, int n_in,
                              void* d_out, int out_size, void* d_ws, size_t ws_size,
                              hipStream_t stream) {
    const float* x   = (const float*)d_in[0];
    const float* w1  = (const float*)d_in[1];
    const float* w2  = (const float*)d_in[2];
    const float* g1  = (const float*)d_in[3];
    const float* b1  = (const float*)d_in[4];
    const float* mu1 = (const float*)d_in[5];
    const float* v1  = (const float*)d_in[6];
    const float* g2  = (const float*)d_in[7];
    const float* b2  = (const float*)d_in[8];
    const float* mu2 = (const float*)d_in[9];
    const float* v2  = (const float*)d_in[10];
    const float* wm1 = (const float*)d_in[11];
    const float* bm1 = (const float*)d_in[12];
    const float* wm2 = (const float*)d_in[13];
    const float* bm2 = (const float*)d_in[14];
    float* out = (float*)d_out;

    // workspace: masks + packed weights + bf16 tmp  (~54.5 MB, ws known >=103 MB)
    float* m1   = (float*)d_ws;                      // NB*HW
    float* m2   = m1 + (size_t)NB*HW;                // NB*HW
    bf16*  w1p  = (bf16*)(m2 + (size_t)NB*HW);       // WELEM
    bf16*  w2p  = w1p + WELEM;                       // WELEM
    bf16*  tmpb = w2p + WELEM;                       // NB*HW*C
    // xb (NHWC bf16, 51.4 MB) lives in d_out: dead until conv2's epilogue.
    bf16*  xb   = (bf16*)d_out;

    mask_kernel<<<(NB*HW)/256, 256, 0, stream>>>(x, wm1, bm1, wm2, bm2, m1, m2);
    transpose_kernel<<<NB*4*49, 256, 0, stream>>>(x, xb);
    pack_kernel<<<2*WELEM/256, 256, 0, stream>>>(w1, w2, w1p, w2p);

    const int grid = NB * 49;    // 1568 blocks: 8x8 pixel tile x full co
    conv_mfma<true ><<<grid, 256, 0, stream>>>(
        xb,   w1p, g1, b1, mu1, v1, m1, nullptr, tmpb, nullptr);
    conv_mfma<false><<<grid, 256, 0, stream>>>(
        tmpb, w2p, g2, b2, mu2, v2, m2, x, nullptr, out);
}

// Round 6
// 701.002 us; speedup vs baseline: 14.8253x; 1.5534x over previous
//
#include <hip/hip_runtime.h>
#include <hip/hip_bf16.h>

// ScaleNet gated residual block, MI355X — bf16 MFMA implicit GEMM.
//  K0a mask_part  : split-K(8) f64-accum mask convs -> partials (ws)
//  K0b mask_reduce: sum partials + bias, threshold -> m1, m2
//  K1 transpose   : x NCHW f32 -> xb NHWC bf16 (stored in d_out scratch)
//  K2 pack        : w1,w2 OIHW f32 -> B-frag-ready packed bf16
//  K3 conv_mfma<1>: conv1 + BN1 + ReLU + *m1 -> tmp NHWC bf16 (ws)
//  K4 conv_mfma<0>: conv2 + BN2 + *m2 + residual + ReLU -> d_out NCHW f32

#define NB 32
#define C  256
#define H  56
#define W  56
#define HW (H*W)          // 3136 = 49*64
#define EPSV 1e-5f
#define WELEM (C*C*9)     // 589824 packed elements per conv
#define NSPLIT 8
#define CSPL (C/NSPLIT)   // 32 channels per split

typedef __hip_bfloat16 bf16;
typedef __attribute__((ext_vector_type(8))) short  bf16x8;
typedef __attribute__((ext_vector_type(4))) float  floatx4;

// ---------------- K0a: mask conv partials (split-K over channels) -----------
// grid = 392 * NSPLIT blocks -> ~12 blocks/CU, latency hidden by TLP.
__global__ __launch_bounds__(256) void mask_part_kernel(
    const float* __restrict__ x,
    const float* __restrict__ wm1, const float* __restrict__ wm2,
    double* __restrict__ p1, double* __restrict__ p2)
{
    __shared__ float ws1[CSPL*9], ws2[CSPL*9];
    int pixb  = blockIdx.x % 392;
    int split = blockIdx.x / 392;
    int c0 = split * CSPL;
    for (int i = threadIdx.x; i < CSPL*9; i += 256) {
        ws1[i] = wm1[c0*9 + i];
        ws2[i] = wm2[c0*9 + i];
    }
    __syncthreads();

    int idx = pixb * 256 + threadIdx.x;   // pixel id, exact
    int w_ = idx % W;
    int t  = idx / W;
    int h  = t % H;
    int n  = t / H;

    double a1 = 0.0, a2 = 0.0;
    const float* xp = x + (size_t)n * C * HW + (size_t)c0 * HW;
    for (int ci = 0; ci < CSPL; ++ci) {
        const float* bp = xp + (size_t)ci * HW;
        #pragma unroll
        for (int ky = 0; ky < 3; ++ky) {
            int y = h + ky - 1;
            if ((unsigned)y >= (unsigned)H) continue;
            #pragma unroll
            for (int kx = 0; kx < 3; ++kx) {
                int xx = w_ + kx - 1;
                if ((unsigned)xx >= (unsigned)W) continue;
                double xv = (double)bp[y*W + xx];
                a1 += xv * (double)ws1[ci*9 + ky*3 + kx];
                a2 += xv * (double)ws2[ci*9 + ky*3 + kx];
            }
        }
    }
    p1[(size_t)split*(NB*HW) + idx] = a1;
    p2[(size_t)split*(NB*HW) + idx] = a2;
}

// ---------------- K0b: reduce partials, threshold ---------------------------
__global__ __launch_bounds__(256) void mask_reduce_kernel(
    const double* __restrict__ p1, const double* __restrict__ p2,
    const float* __restrict__ bm1, const float* __restrict__ bm2,
    float* __restrict__ m1, float* __restrict__ m2)
{
    int idx = blockIdx.x * 256 + threadIdx.x;
    double a1 = (double)bm1[0], a2 = (double)bm2[0];
    #pragma unroll
    for (int s = 0; s < NSPLIT; ++s) {
        a1 += p1[(size_t)s*(NB*HW) + idx];
        a2 += p2[(size_t)s*(NB*HW) + idx];
    }
    m1[idx] = (a1 > 0.0) ? 1.0f : 0.0f;   // sigmoid(z)>0.5 <=> z>0
    m2[idx] = (a2 > 0.0) ? 1.0f : 0.0f;
}

// ---------------- K1: NCHW f32 -> NHWC bf16 ---------------------------------
__global__ __launch_bounds__(256) void transpose_kernel(
    const float* __restrict__ x, bf16* __restrict__ xb)
{
    __shared__ float tile[64][65];
    int bid = blockIdx.x;             // 32 * 4 * 49
    int pt = bid % 49; bid /= 49;
    int ct = bid % 4;  int n = bid / 4;
    int p0 = pt * 64, c0 = ct * 64;
    int tl = threadIdx.x & 63;
    int tg = threadIdx.x >> 6;        // 0..3
    const float* xp = x + ((size_t)(n*C + c0) * HW) + p0;
    #pragma unroll
    for (int i = 0; i < 16; ++i) {
        int cl = tg*16 + i;
        tile[cl][tl] = xp[(size_t)cl * HW + tl];
    }
    __syncthreads();
    bf16* op = xb + ((size_t)(n*HW + p0) * C) + c0;
    #pragma unroll
    for (int i = 0; i < 16; ++i) {
        int pl = tg*16 + i;
        op[(size_t)pl * C + tl] = __float2bfloat16(tile[tl][pl]);
    }
}

// ---------------- K2: pack weights into B-frag order ------------------------
// layout: [tap(9)][kstep(8)][ntile(16)][lane(64)][8 ci]  (16B per lane)
__global__ __launch_bounds__(256) void pack_kernel(
    const float* __restrict__ w1, const float* __restrict__ w2,
    bf16* __restrict__ w1p, bf16* __restrict__ w2p)
{
    int idx = blockIdx.x * 256 + threadIdx.x;       // 0 .. 2*WELEM-1
    const float* src = (idx < WELEM) ? w1 : w2;
    bf16* dst        = (idx < WELEM) ? w1p : w2p;
    int f = (idx < WELEM) ? idx : idx - WELEM;
    int e  = f & 7;
    int O  = f >> 3;
    int L  = O & 63;
    int j  = (O >> 6) & 15;
    int ks = (O >> 10) & 7;
    int t  = O >> 13;
    int co = j*16 + (L & 15);
    int ci = ks*32 + ((L >> 4) & 3)*8 + e;
    dst[f] = __float2bfloat16(src[((size_t)co*C + ci)*9 + t]);
}

// ---------------- K3/K4: MFMA implicit-GEMM conv ----------------------------
// block: 64 pixels (8x8 tile) x 256 co, 4 waves (64 co each), K chunked 128.
template<bool FIRST>
__global__ __launch_bounds__(256, 2) void conv_mfma(
    const bf16* __restrict__ inb,    // NHWC bf16
    const bf16* __restrict__ wp,     // packed weights
    const float* __restrict__ g,  const float* __restrict__ b,
    const float* __restrict__ mu, const float* __restrict__ vv,
    const float* __restrict__ mask,  // [NB][HW] 0/1
    const float* __restrict__ xres,  // NCHW f32 (SECOND)
    bf16* __restrict__ outb,         // FIRST: tmp NHWC bf16
    float* __restrict__ outf)        // SECOND: NCHW f32
{
    __shared__ uint4 patch4[1700];   // 100 pos * (128 ci + 8 pad) shorts = 27.2 KB
    __shared__ float msk[64];
    short* patch = (short*)patch4;

    int bid  = blockIdx.x;
    int tile = bid % 49;
    int n    = bid / 49;
    int y0 = (tile / 7) * 8;
    int x0 = (tile % 7) * 8;

    int tid = threadIdx.x;
    int L   = tid & 63;
    int wv  = tid >> 6;

    if (tid < 64) {
        int pr = tid >> 3, pc = tid & 7;
        msk[tid] = mask[(size_t)n*HW + (y0+pr)*W + (x0+pc)];
    }

    // per-lane A-fragment base offsets (padded stride 136 shorts/position)
    int m  = L & 15;
    int kb = L >> 4;
    int abase[4];
    #pragma unroll
    for (int mi = 0; mi < 4; ++mi) {
        int p   = mi*16 + m;
        int pos = (p >> 3)*10 + (p & 7);
        abase[mi] = pos*136 + kb*8;
    }

    floatx4 acc[4][4];
    #pragma unroll
    for (int mi = 0; mi < 4; ++mi)
        #pragma unroll
        for (int jj = 0; jj < 4; ++jj)
            acc[mi][jj] = (floatx4){0.f, 0.f, 0.f, 0.f};

    const size_t img_base = (size_t)n * HW * C;

    for (int ck = 0; ck < 2; ++ck) {
        if (ck) __syncthreads();                 // LDS reuse fence
        // ---- stage 10x10 halo patch, 128-ci chunk, into LDS ----
        for (int S = tid; S < 1600; S += 256) {
            int q   = S & 15;
            int pos = S >> 4;
            int r = pos / 10, c = pos - (pos/10)*10;
            int y  = y0 + r - 1;
            int xx = x0 + c - 1;
            uint4 val = make_uint4(0u, 0u, 0u, 0u);
            if ((unsigned)y < (unsigned)H && (unsigned)xx < (unsigned)W)
                val = *(const uint4*)(inb + img_base + (size_t)(y*W + xx)*C + ck*128 + q*8);
            patch4[pos*17 + q] = val;
        }
        __syncthreads();

        // ---- K-loop: 9 taps x 4 ksteps, register-double-buffered B ----
        bf16x8 bcur[4], bnxt[4];
        {
            int ks0 = ck*4;
            #pragma unroll
            for (int jj = 0; jj < 4; ++jj) {
                int jgl = wv*4 + jj;
                bcur[jj] = *(const bf16x8*)(wp + ((size_t)((0*8 + ks0)*16 + jgl)*64 + L)*8);
            }
        }
        for (int gs = 0; gs < 36; ++gs) {
            int t = gs >> 2;
            int s = gs & 3;
            if (gs < 35) {
                int g2 = gs + 1;
                int t2 = g2 >> 2, ks2 = ck*4 + (g2 & 3);
                #pragma unroll
                for (int jj = 0; jj < 4; ++jj) {
                    int jgl = wv*4 + jj;
                    bnxt[jj] = *(const bf16x8*)(wp + ((size_t)((t2*8 + ks2)*16 + jgl)*64 + L)*8);
                }
            }
            int ky = t / 3;
            int dt = ky*10 + (t - ky*3);         // ky*10 + kx
            int aoff = dt*136 + s*32;
            bf16x8 afr[4];
            #pragma unroll
            for (int mi = 0; mi < 4; ++mi)
                afr[mi] = *(const bf16x8*)(patch + abase[mi] + aoff);
            #pragma unroll
            for (int mi = 0; mi < 4; ++mi)
                #pragma unroll
                for (int jj = 0; jj < 4; ++jj)
                    acc[mi][jj] = __builtin_amdgcn_mfma_f32_16x16x32_bf16(
                        afr[mi], bcur[jj], acc[mi][jj], 0, 0, 0);
            #pragma unroll
            for (int jj = 0; jj < 4; ++jj) bcur[jj] = bnxt[jj];
        }
    }

    // ---- epilogue ----
    int quad  = L >> 4;
    int wbase = wv * 64;
    #pragma unroll
    for (int jj = 0; jj < 4; ++jj) {
        int co = wbase + jj*16 + (L & 15);
        float s_ = g[co] * rsqrtf(vv[co] + EPSV);
        float t_ = b[co] - mu[co] * s_;
        #pragma unroll
        for (int mi = 0; mi < 4; ++mi) {
            int pbase = mi*16 + quad*4;
            if (FIRST) {
                #pragma unroll
                for (int r = 0; r < 4; ++r) {
                    int p = pbase + r;
                    float v = acc[mi][jj][r] * s_ + t_;
                    v = fmaxf(v, 0.f) * msk[p];
                    int pg = (y0 + (p >> 3))*W + (x0 + (p & 7));
                    outb[img_base + (size_t)pg*C + co] = __float2bfloat16(v);
                }
            } else {
                int pg = (y0 + (pbase >> 3))*W + (x0 + (pbase & 7));
                size_t oidx = ((size_t)(n*C + co))*HW + pg;
                floatx4 xr = *(const floatx4*)(xres + oidx);
                floatx4 ov;
                #pragma unroll
                for (int r = 0; r < 4; ++r) {
                    float v = acc[mi][jj][r] * s_ + t_;
                    v = v * msk[pbase + r] + xr[r];
                    ov[r] = fmaxf(v, 0.f);
                }
                *(floatx4*)(outf + oidx) = ov;
            }
        }
    }
}

extern "C" void kernel_launch(void* const* d_in, const int* in_sizes, int n_in,
                              void* d_out, int out_size, void* d_ws, size_t ws_size,
                              hipStream_t stream) {
    const float* x   = (const float*)d_in[0];
    const float* w1  = (const float*)d_in[1];
    const float* w2  = (const float*)d_in[2];
    const float* g1  = (const float*)d_in[3];
    const float* b1  = (const float*)d_in[4];
    const float* mu1 = (const float*)d_in[5];
    const float* v1  = (const float*)d_in[6];
    const float* g2  = (const float*)d_in[7];
    const float* b2  = (const float*)d_in[8];
    const float* mu2 = (const float*)d_in[9];
    const float* v2  = (const float*)d_in[10];
    const float* wm1 = (const float*)d_in[11];
    const float* bm1 = (const float*)d_in[12];
    const float* wm2 = (const float*)d_in[13];
    const float* bm2 = (const float*)d_in[14];
    float* out = (float*)d_out;

    // workspace (~67.4 MB; R3 proved ws >= 103.6 MB):
    float* m1   = (float*)d_ws;                      // NB*HW
    float* m2   = m1 + (size_t)NB*HW;                // NB*HW
    bf16*  w1p  = (bf16*)(m2 + (size_t)NB*HW);       // WELEM
    bf16*  w2p  = w1p + WELEM;                       // WELEM
    bf16*  tmpb = w2p + WELEM;                       // NB*HW*C bf16
    double* p1  = (double*)(tmpb + (size_t)NB*HW*C); // NSPLIT*NB*HW f64
    double* p2  = p1 + (size_t)NSPLIT*NB*HW;         // NSPLIT*NB*HW f64
    // xb (NHWC bf16, 51.4 MB) lives in d_out: dead until conv2's epilogue.
    bf16*  xb   = (bf16*)d_out;

    mask_part_kernel<<<392*NSPLIT, 256, 0, stream>>>(x, wm1, wm2, p1, p2);
    mask_reduce_kernel<<<392, 256, 0, stream>>>(p1, p2, bm1, bm2, m1, m2);
    transpose_kernel<<<NB*4*49, 256, 0, stream>>>(x, xb);
    pack_kernel<<<2*WELEM/256, 256, 0, stream>>>(w1, w2, w1p, w2p);

    const int grid = NB * 49;    // 1568 blocks: 8x8 pixel tile x full co
    conv_mfma<true ><<<grid, 256, 0, stream>>>(
        xb,   w1p, g1, b1, mu1, v1, m1, nullptr, tmpb, nullptr);
    conv_mfma<false><<<grid, 256, 0, stream>>>(
        tmpb, w2p, g2, b2, mu2, v2, m2, x, nullptr, out);
}